// Round 4
// baseline (3509.302 us; speedup 1.0000x reference)
//
#include <hip/hip_runtime.h>

// B*H*W = 65536 vectors, dim 64, 512 codes
#define NVEC 65536
#define DIM 64
#define KCODES 512
#define NBLK 1024  // NVEC / 64

// Block: 256 threads = 4 waves, all covering the SAME 64 vectors (one per
// lane; z[64] pinned in VGPRs via asm). Each wave scans a wave-uniform slice
// of 128 codes, staged per-wave into LDS in double-buffered 16-code tiles
// (reg-staged: global->reg early, ds_write late; no block barriers in the
// main loop, so the 4 waves/SIMD hide each other's latencies). Inner loop
// reads emb via uniform-address ds_read_b128 broadcasts (conflict-free).
// Grid: 1024 blocks = 4 blocks/CU = 4 waves/SIMD.
__global__ __launch_bounds__(256, 4) void vq_kernel(const float* __restrict__ x,
                                                    const float* __restrict__ emb,
                                                    float* __restrict__ out,
                                                    float* __restrict__ ws) {
    __shared__ float ebuf[2][4][DIM * 16];  // [parity][wave][d*16+kloc] = 32 KB
    __shared__ float en[KCODES];            // ||e_k||^2
    __shared__ float sdist[4][64];
    __shared__ int   sidx[4][64];
    __shared__ float swl[4];

    const int tid  = threadIdx.x;
    const int wid  = __builtin_amdgcn_readfirstlane(tid >> 6);  // 0..3 (SGPR)
    const int lane = tid & 63;

    // --- codebook norms: coalesced over k ---
    for (int kk = tid; kk < KCODES; kk += 256) {
        float s = 0.f;
#pragma unroll
        for (int d = 0; d < DIM; ++d) {
            float v = emb[d * KCODES + kk];
            s = fmaf(v, v, s);
        }
        en[kk] = s;
    }

    // --- z into registers + ||z||^2, then PIN z (stop rematerialization) ---
    const int vec = blockIdx.x * 64 + lane;
    const float* xv = x + (size_t)vec * DIM;
    float z[DIM];
#pragma unroll
    for (int d = 0; d < DIM; d += 4) {
        float4 v = *reinterpret_cast<const float4*>(xv + d);
        z[d] = v.x; z[d + 1] = v.y; z[d + 2] = v.z; z[d + 3] = v.w;
    }
    float znorm = 0.f;
#pragma unroll
    for (int d = 0; d < DIM; ++d) znorm = fmaf(z[d], z[d], znorm);
#pragma unroll
    for (int d = 0; d < DIM; ++d) asm volatile("" : "+v"(z[d]));

    __syncthreads();  // en[] ready

    const int kb0 = wid * 128;           // this wave's code slice
    const int r0  = lane >> 2;           // staging geometry: 16B per lane
    const int c0  = (lane & 3) * 4;

    // --- prologue: stage tile 0 into parity 0 (this wave's buffer only) ---
    {
        float4 st[4];
#pragma unroll
        for (int i = 0; i < 4; ++i)
            st[i] = *reinterpret_cast<const float4*>(emb + (i * 16 + r0) * KCODES + kb0 + c0);
        float4* lp = reinterpret_cast<float4*>(&ebuf[0][wid][0]);
#pragma unroll
        for (int i = 0; i < 4; ++i) lp[i * 64 + lane] = st[i];
    }

    float best  = 3.4e38f;
    int   bestk = 0;

#pragma unroll 1
    for (int t = 0; t < 8; ++t) {
        const int kb = kb0 + t * 16;
        // issue next tile's global loads BEFORE compute (latency hides under FMAs)
        float4 stn[4];
        if (t < 7) {
#pragma unroll
            for (int i = 0; i < 4; ++i)
                stn[i] = *reinterpret_cast<const float4*>(emb + (i * 16 + r0) * KCODES + kb + 16 + c0);
        }

        const float4* ep = reinterpret_cast<const float4*>(&ebuf[t & 1][wid][0]);
#pragma unroll
        for (int g = 0; g < 2; ++g) {
            float acc[8] = {0.f, 0.f, 0.f, 0.f, 0.f, 0.f, 0.f, 0.f};
#pragma unroll
            for (int d = 0; d < DIM; ++d) {
                float4 e0 = ep[d * 4 + g * 2];      // uniform addr -> LDS broadcast
                float4 e1 = ep[d * 4 + g * 2 + 1];
                acc[0] = fmaf(z[d], e0.x, acc[0]);
                acc[1] = fmaf(z[d], e0.y, acc[1]);
                acc[2] = fmaf(z[d], e0.z, acc[2]);
                acc[3] = fmaf(z[d], e0.w, acc[3]);
                acc[4] = fmaf(z[d], e1.x, acc[4]);
                acc[5] = fmaf(z[d], e1.y, acc[5]);
                acc[6] = fmaf(z[d], e1.z, acc[6]);
                acc[7] = fmaf(z[d], e1.w, acc[7]);
            }
            float4 en0 = *reinterpret_cast<const float4*>(&en[kb + g * 8]);
            float4 en1 = *reinterpret_cast<const float4*>(&en[kb + g * 8 + 4]);
            float ens[8] = {en0.x, en0.y, en0.z, en0.w, en1.x, en1.y, en1.z, en1.w};
#pragma unroll
            for (int j = 0; j < 8; ++j) {
                // reference association: (||z||^2 + ||e||^2) - 2*dot
                float tt   = znorm + ens[j];
                float dist = fmaf(-2.0f, acc[j], tt);
                if (dist < best) { best = dist; bestk = kb + g * 8 + j; }  // ascending k
            }
        }

        // write next tile to the other parity (consumed next iteration)
        if (t < 7) {
            float4* lp = reinterpret_cast<float4*>(&ebuf[(t + 1) & 1][wid][0]);
#pragma unroll
            for (int i = 0; i < 4; ++i) lp[i * 64 + lane] = stn[i];
        }
    }

    sdist[wid][lane] = best;
    sidx[wid][lane]  = bestk;
    __syncthreads();

    // --- epilogue: thread t -> vector v16 = t>>2, dim-block j16 = (t&3)*16 ---
    const int v16 = tid >> 2;
    const int j16 = (tid & 3) * 16;
    float bd = sdist[0][v16];
    int   bk = sidx[0][v16];
#pragma unroll
    for (int s = 1; s < 4; ++s) {  // ascending-k slices; strict < keeps lowest k
        float d2 = sdist[s][v16];
        int   k2 = sidx[s][v16];
        if (d2 < bd) { bd = d2; bk = k2; }
    }

    const int gvec = blockIdx.x * 64 + v16;
    const float* xg = x + (size_t)gvec * DIM + j16;
    float*       og = out + (size_t)gvec * DIM + j16;

    float lossLocal = 0.f;
#pragma unroll
    for (int c = 0; c < 4; ++c) {
        float4 q;
        q.x = emb[(j16 + c * 4 + 0) * KCODES + bk];
        q.y = emb[(j16 + c * 4 + 1) * KCODES + bk];
        q.z = emb[(j16 + c * 4 + 2) * KCODES + bk];
        q.w = emb[(j16 + c * 4 + 3) * KCODES + bk];
        *reinterpret_cast<float4*>(og + c * 4) = q;  // 4 KB contiguous per wave
        float4 xa = *reinterpret_cast<const float4*>(xg + c * 4);
        float a;
        a = q.x - xa.x; lossLocal = fmaf(a, a, lossLocal);
        a = q.y - xa.y; lossLocal = fmaf(a, a, lossLocal);
        a = q.z - xa.z; lossLocal = fmaf(a, a, lossLocal);
        a = q.w - xa.w; lossLocal = fmaf(a, a, lossLocal);
    }

    // --- block-reduce loss, atomic accumulate, last block finalizes ---
#pragma unroll
    for (int off = 32; off; off >>= 1) lossLocal += __shfl_down(lossLocal, off, 64);
    if (lane == 0) swl[wid] = lossLocal;
    __syncthreads();
    if (tid == 0) {
        float s = swl[0] + swl[1] + swl[2] + swl[3];
        atomicAdd(&ws[0], s);
        __threadfence();
        unsigned int* cnt = reinterpret_cast<unsigned int*>(ws + 1);
        unsigned int prev = atomicAdd(cnt, 1u);
        if (prev == (unsigned int)(NBLK - 1)) {
            float total = atomicAdd(&ws[0], 0.0f);  // coherent read of final sum
            out[(size_t)NVEC * DIM] = 2.0f * total / (float)((size_t)NVEC * DIM);
        }
    }
}

extern "C" void kernel_launch(void* const* d_in, const int* in_sizes, int n_in,
                              void* d_out, int out_size, void* d_ws, size_t ws_size,
                              hipStream_t stream) {
    const float* x   = (const float*)d_in[0];
    const float* emb = (const float*)d_in[1];
    float* out = (float*)d_out;
    float* ws  = (float*)d_ws;

    hipMemsetAsync(d_ws, 0, 8, stream);  // loss accumulator + block counter
    vq_kernel<<<dim3(NBLK), dim3(256), 0, stream>>>(x, emb, out, ws);
}

// Round 5
// 128.178 us; speedup vs baseline: 27.3783x; 27.3783x over previous
//
#include <hip/hip_runtime.h>

// B*H*W = 65536 vectors, dim 64, 512 codes
#define NVEC 65536
#define DIM 64
#define KCODES 512
#define NBLK 1024  // NVEC / 64

// Block: 256 threads = 4 waves, all covering the SAME 64 vectors (one per
// lane). Each wave scans a wave-uniform slice of 128 codes -> emb reads are
// scalar s_load_dwordx8 broadcasts (zero VALU issue cost). z[64] is held in
// VGPRs and PINNED via empty asm so the allocator cannot rematerialize the
// x loads inside the k-loop (R2/R3 failure). __launch_bounds__(256,2) gives
// a 256-VGPR budget so the pin cannot force spills (R4 failure: pin + 64-VGPR
// allocation = 12 GB of scratch traffic).
// Grid: 1024 blocks = 4 blocks/CU = 4 waves/SIMD (grid-capped).
__global__ __launch_bounds__(256, 2) void vq_kernel(const float* __restrict__ x,
                                                    const float* __restrict__ emb,
                                                    float* __restrict__ out,
                                                    float* __restrict__ ws) {
    __shared__ float en[KCODES];     // ||e_k||^2
    __shared__ float sdist[4][64];
    __shared__ int   sidx[4][64];
    __shared__ float swl[4];

    const int tid = threadIdx.x;

    // --- codebook norms: coalesced over k ---
    for (int kk = tid; kk < KCODES; kk += 256) {
        float s = 0.f;
#pragma unroll
        for (int d = 0; d < DIM; ++d) {
            float v = emb[d * KCODES + kk];
            s = fmaf(v, v, s);
        }
        en[kk] = s;
    }

    const int wid  = __builtin_amdgcn_readfirstlane(tid >> 6);  // 0..3, SGPR
    const int lane = tid & 63;
    const int vec  = blockIdx.x * 64 + lane;
    const float* xv = x + (size_t)vec * DIM;

    // --- z fully in registers + ||z||^2, then PIN z ---
    float z[DIM];
#pragma unroll
    for (int d = 0; d < DIM; d += 4) {
        float4 v = *reinterpret_cast<const float4*>(xv + d);
        z[d] = v.x; z[d + 1] = v.y; z[d + 2] = v.z; z[d + 3] = v.w;
    }
    float znorm = 0.f;
#pragma unroll
    for (int d = 0; d < DIM; ++d) znorm = fmaf(z[d], z[d], znorm);
#pragma unroll
    for (int d = 0; d < DIM; ++d) asm volatile("" : "+v"(z[d]));

    __syncthreads();  // en[] ready

    // --- scan this wave's 128-code slice, 8 codes per tile ---
    float best  = 3.4e38f;
    int   bestk = 0;
    const int kbase0 = wid * 128;  // wave-uniform
#pragma unroll 1
    for (int kt = 0; kt < 16; ++kt) {
        const int kb = kbase0 + kt * 8;
        float acc[8] = {0.f, 0.f, 0.f, 0.f, 0.f, 0.f, 0.f, 0.f};
#pragma unroll
        for (int d = 0; d < DIM; ++d) {
            const float* ep = emb + d * KCODES + kb;  // wave-uniform -> s_load_dwordx8
#pragma unroll
            for (int j = 0; j < 8; ++j) acc[j] = fmaf(z[d], ep[j], acc[j]);
        }
#pragma unroll
        for (int j = 0; j < 8; ++j) {
            // reference association: (||z||^2 + ||e||^2) - 2*dot
            float t    = znorm + en[kb + j];
            float dist = fmaf(-2.0f, acc[j], t);
            if (dist < best) { best = dist; bestk = kb + j; }  // ascending k, first min wins
        }
    }

    sdist[wid][lane] = best;
    sidx[wid][lane]  = bestk;
    __syncthreads();

    // --- epilogue: thread t -> vector v16 = t>>2, dim-block j16 = (t&3)*16 ---
    const int v16 = tid >> 2;
    const int j16 = (tid & 3) * 16;
    float bd = sdist[0][v16];
    int   bk = sidx[0][v16];
#pragma unroll
    for (int s = 1; s < 4; ++s) {   // ascending-k slices; strict < keeps lowest k
        float d2 = sdist[s][v16];
        int   k2 = sidx[s][v16];
        if (d2 < bd) { bd = d2; bk = k2; }
    }

    const int gvec = blockIdx.x * 64 + v16;
    const float* xg = x + (size_t)gvec * DIM + j16;
    float*       og = out + (size_t)gvec * DIM + j16;

    float lossLocal = 0.f;
#pragma unroll
    for (int c = 0; c < 4; ++c) {
        float4 q;
        q.x = emb[(j16 + c * 4 + 0) * KCODES + bk];
        q.y = emb[(j16 + c * 4 + 1) * KCODES + bk];
        q.z = emb[(j16 + c * 4 + 2) * KCODES + bk];
        q.w = emb[(j16 + c * 4 + 3) * KCODES + bk];
        *reinterpret_cast<float4*>(og + c * 4) = q;  // contiguous 4 KB per wave
        float4 xa = *reinterpret_cast<const float4*>(xg + c * 4);
        float a;
        a = q.x - xa.x; lossLocal = fmaf(a, a, lossLocal);
        a = q.y - xa.y; lossLocal = fmaf(a, a, lossLocal);
        a = q.z - xa.z; lossLocal = fmaf(a, a, lossLocal);
        a = q.w - xa.w; lossLocal = fmaf(a, a, lossLocal);
    }

    // --- block-reduce loss, atomic accumulate, last block finalizes ---
#pragma unroll
    for (int off = 32; off; off >>= 1) lossLocal += __shfl_down(lossLocal, off, 64);
    if (lane == 0) swl[wid] = lossLocal;
    __syncthreads();
    if (tid == 0) {
        float s = swl[0] + swl[1] + swl[2] + swl[3];
        atomicAdd(&ws[0], s);
        __threadfence();
        unsigned int* cnt = reinterpret_cast<unsigned int*>(ws + 1);
        unsigned int prev = atomicAdd(cnt, 1u);
        if (prev == (unsigned int)(NBLK - 1)) {
            float total = atomicAdd(&ws[0], 0.0f);  // coherent read of final sum
            out[(size_t)NVEC * DIM] = 2.0f * total / (float)((size_t)NVEC * DIM);
        }
    }
}

extern "C" void kernel_launch(void* const* d_in, const int* in_sizes, int n_in,
                              void* d_out, int out_size, void* d_ws, size_t ws_size,
                              hipStream_t stream) {
    const float* x   = (const float*)d_in[0];
    const float* emb = (const float*)d_in[1];
    float* out = (float*)d_out;
    float* ws  = (float*)d_ws;

    hipMemsetAsync(d_ws, 0, 8, stream);  // loss accumulator + block counter
    vq_kernel<<<dim3(NBLK), dim3(256), 0, stream>>>(x, emb, out, ws);
}